// Round 1
// baseline (496.505 us; speedup 1.0000x reference)
//
#include <hip/hip_runtime.h>

using bf16x8 = __attribute__((ext_vector_type(8))) short;
using f32x4  = __attribute__((ext_vector_type(4))) float;

#define NH    16
#define DKH   64
#define TTOT  2048
#define QL    1024

__device__ __forceinline__ float bf2f(unsigned short u) {
  union { unsigned int i; float f; } c; c.i = ((unsigned int)u) << 16; return c.f;
}
__device__ __forceinline__ unsigned short f2bf(float f) {
  union { float f; unsigned int i; } c; c.f = f;
  unsigned int x = c.i;
  x += 0x7fffu + ((x >> 16) & 1u);
  return (unsigned short)(x >> 16);
}
// XOR swizzle inside each row (byte bits 4..6 ^= row&7) for the 32x2048 bf16 LDS tile
__device__ __forceinline__ int swz(int r, int c) {
  return r * 2048 + ((((c << 1) ^ ((r & 7) << 4))) >> 1);
}
__device__ __forceinline__ f32x4 mfma16(bf16x8 a, bf16x8 b, f32x4 c) {
  return __builtin_amdgcn_mfma_f32_16x16x32_bf16(a, b, c, 0, 0, 0);
}

// ---------------- convert fp32 inputs -> bf16 workspace ----------------
__global__ void convert_all(
    const float* __restrict__ key, const float* __restrict__ query,
    const float* __restrict__ memory, const float* __restrict__ pos,
    const int* __restrict__ mask,
    const float* __restrict__ Wk, const float* __restrict__ Wv,
    const float* __restrict__ Wq, const float* __restrict__ Wp,
    const float* __restrict__ Wo,
    unsigned short* __restrict__ kcat, unsigned short* __restrict__ qbf,
    unsigned short* __restrict__ posb,
    unsigned short* __restrict__ wkb, unsigned short* __restrict__ wvb,
    unsigned short* __restrict__ wqb, unsigned short* __restrict__ wpb,
    unsigned short* __restrict__ wob, unsigned short* __restrict__ mkb)
{
  const int n0 = 4194304;            // kcat  (B*T*1024)
  const int n1 = n0 + 2097152;       // query
  const int n2 = n1 + 2097152;       // pos
  const int n3 = n2 + 1048576;       // Wk
  const int n4 = n3 + 1048576;       // Wv
  const int n5 = n4 + 1048576;       // Wq
  const int n6 = n5 + 1048576;       // Wp
  const int n7 = n6 + 1048576;       // Wo
  const int n8 = n7 + 4194304;       // mask
  for (int i = blockIdx.x * blockDim.x + threadIdx.x; i < n8;
       i += gridDim.x * blockDim.x) {
    if (i < n0) {
      int b = i >> 21, r = i & ((1 << 21) - 1);
      int t = r >> 10, c = r & 1023;
      float v = (t < 1024) ? memory[((size_t)b << 20) + (t << 10) + c]
                           : key[((size_t)b << 20) + ((t - 1024) << 10) + c];
      kcat[i] = f2bf(v);
    } else if (i < n1) { int j = i - n0; qbf[j]  = f2bf(query[j]); }
    else if (i < n2)   { int j = i - n1; posb[j] = f2bf(pos[j]); }
    else if (i < n3)   { int j = i - n2; wkb[j]  = f2bf(Wk[j]); }
    else if (i < n4)   { int j = i - n3; wvb[j]  = f2bf(Wv[j]); }
    else if (i < n5)   { int j = i - n4; wqb[j]  = f2bf(Wq[j]); }
    else if (i < n6)   { int j = i - n5; wpb[j]  = f2bf(Wp[j]); }
    else if (i < n7)   { int j = i - n6; wob[j]  = f2bf(Wo[j]); }
    else { int j = i - n7; mkb[j] = mask[j] ? (unsigned short)0 : f2bf(-1e30f); }
  }
}

// ---------------- generic 128x128 bf16 GEMM:  C = A @ Bw^T + bias ----------------
// MODE 0: bf16 out, head-split layout  out0[((b*H+h)*rows_per_b + t)*64 + d]
// MODE 1: two bf16 outs (+u, +v) head-split (q projection)
// MODE 2: fp32 row-major out (final projection)
template<int MODE>
__global__ __launch_bounds__(256, 2) void gemm_bt(
    const unsigned short* __restrict__ A, const unsigned short* __restrict__ Bw,
    const float* __restrict__ bias, const float* __restrict__ uvec,
    const float* __restrict__ vvec,
    unsigned short* __restrict__ out0, unsigned short* __restrict__ out1,
    float* __restrict__ outf, int M, int rpb_shift)
{
  constexpr int K = 1024;
  __shared__ unsigned short sA[128 * 32];
  __shared__ unsigned short sB[128 * 32];
  const int tid = threadIdx.x;
  const int lane = tid & 63;
  const int wid = tid >> 6;
  const int wm = (wid >> 1) * 64, wn = (wid & 1) * 64;
  const int bm = blockIdx.y * 128, bn = blockIdx.x * 128;
  const int l15 = lane & 15, l4 = lane >> 4;

  const int c0 = tid, c1 = tid + 256;
  const int am0 = c0 >> 2, as0 = c0 & 3;
  const int am1 = c1 >> 2, as1 = c1 & 3;
  const unsigned short* Ap0 = A + (size_t)(bm + am0) * K + as0 * 8;
  const unsigned short* Ap1 = A + (size_t)(bm + am1) * K + as1 * 8;
  const unsigned short* Bp0 = Bw + (size_t)(bn + am0) * K + as0 * 8;
  const unsigned short* Bp1 = Bw + (size_t)(bn + am1) * K + as1 * 8;
  const int swA0 = am0 * 32 + ((as0 ^ ((am0 >> 1) & 3)) * 8);
  const int swA1 = am1 * 32 + ((as1 ^ ((am1 >> 1) & 3)) * 8);

  f32x4 acc[4][4] = {};
  bf16x8 ra0 = *(const bf16x8*)Ap0;
  bf16x8 ra1 = *(const bf16x8*)Ap1;
  bf16x8 rb0 = *(const bf16x8*)Bp0;
  bf16x8 rb1 = *(const bf16x8*)Bp1;

  for (int kt = 0; kt < K / 32; ++kt) {
    *(bf16x8*)(sA + swA0) = ra0;
    *(bf16x8*)(sA + swA1) = ra1;
    *(bf16x8*)(sB + swA0) = rb0;
    *(bf16x8*)(sB + swA1) = rb1;
    __syncthreads();
    if (kt + 1 < K / 32) {
      const int o = (kt + 1) * 32;
      ra0 = *(const bf16x8*)(Ap0 + o);
      ra1 = *(const bf16x8*)(Ap1 + o);
      rb0 = *(const bf16x8*)(Bp0 + o);
      rb1 = *(const bf16x8*)(Bp1 + o);
    }
    bf16x8 af[4], bfr[4];
    #pragma unroll
    for (int mi = 0; mi < 4; ++mi) {
      int row = wm + mi * 16 + l15;
      af[mi] = *(const bf16x8*)(sA + row * 32 + ((l4 ^ ((row >> 1) & 3)) * 8));
    }
    #pragma unroll
    for (int ni = 0; ni < 4; ++ni) {
      int row = wn + ni * 16 + l15;
      bfr[ni] = *(const bf16x8*)(sB + row * 32 + ((l4 ^ ((row >> 1) & 3)) * 8));
    }
    #pragma unroll
    for (int mi = 0; mi < 4; ++mi)
      #pragma unroll
      for (int ni = 0; ni < 4; ++ni)
        acc[mi][ni] = mfma16(af[mi], bfr[ni], acc[mi][ni]);
    __syncthreads();
  }

  #pragma unroll
  for (int mi = 0; mi < 4; ++mi) {
    #pragma unroll
    for (int ni = 0; ni < 4; ++ni) {
      const int col = bn + wn + ni * 16 + l15;
      const float bval = bias[col];
      #pragma unroll
      for (int j = 0; j < 4; ++j) {
        const int row = bm + wm + mi * 16 + l4 * 4 + j;
        const float cv = acc[mi][ni][j] + bval;
        if (MODE == 0) {
          const int b = row >> rpb_shift;
          const int t = row & ((1 << rpb_shift) - 1);
          const size_t o =
              (((size_t)(b * NH + (col >> 6)) << rpb_shift) + t) * DKH + (col & 63);
          out0[o] = f2bf(cv);
        } else if (MODE == 1) {
          const int b = row >> rpb_shift;
          const int t = row & ((1 << rpb_shift) - 1);
          const size_t o =
              (((size_t)(b * NH + (col >> 6)) << rpb_shift) + t) * DKH + (col & 63);
          out0[o] = f2bf(cv + uvec[col]);
          out1[o] = f2bf(cv + vvec[col]);
        } else {
          outf[(size_t)row * 1024 + col] = cv;
        }
      }
    }
  }
}

// ---------------- V transpose: [bh][t][dk] -> [bh][dk][t] ----------------
__global__ void transpose_v(const unsigned short* __restrict__ vbf,
                            unsigned short* __restrict__ vt)
{
  const int bh = blockIdx.y;
  const int t = blockIdx.x * 256 + threadIdx.x;
  for (int dk = 0; dk < 64; ++dk)
    vt[((size_t)bh * DKH + dk) * TTOT + t] = vbf[((size_t)bh * TTOT + t) * DKH + dk];
}

// ---------------- fused scores + rel_shift + softmax + aw write + PV ----------------
__global__ __launch_bounds__(512, 2) void attn_fused(
    const unsigned short* __restrict__ qu, const unsigned short* __restrict__ qv,
    const unsigned short* __restrict__ kb, const unsigned short* __restrict__ pb,
    const unsigned short* __restrict__ vt, const unsigned short* __restrict__ mkb,
    float* __restrict__ awout, unsigned short* __restrict__ cvb)
{
  __shared__ unsigned short sbd[32 * 2048];   // 128 KB: shifted-BD, later aw(bf16)
  __shared__ float sred[2][4][32];
  const int tid = threadIdx.x;
  const int lane = tid & 63;
  const int w = tid >> 6;
  const int l15 = lane & 15, l4 = lane >> 4;
  const int bh = blockIdx.y;
  const int b = bh >> 4, h = bh & 15;
  const int I0 = blockIdx.x * 32;
  const int rt = w >> 2, cc = w & 3;

  // ---- P1: BD via MFMA, scatter-written through the rel_shift mapping ----
  {
    const unsigned short* qvb = qv + (size_t)bh * QL * DKH;
    const unsigned short* pbh = pb + (size_t)h * TTOT * DKH;
    {
      const int arow = I0 + rt * 16 + l15;
      bf16x8 a0 = *(const bf16x8*)(qvb + (size_t)arow * DKH + l4 * 8);
      bf16x8 a1 = *(const bf16x8*)(qvb + (size_t)arow * DKH + 32 + l4 * 8);
      #pragma unroll 4
      for (int nj = 0; nj < 32; ++nj) {
        const int jj = cc * 512 + nj * 16 + l15;
        bf16x8 b0 = *(const bf16x8*)(pbh + (size_t)jj * DKH + l4 * 8);
        bf16x8 b1 = *(const bf16x8*)(pbh + (size_t)jj * DKH + 32 + l4 * 8);
        f32x4 c = {0.f, 0.f, 0.f, 0.f};
        c = mfma16(a0, b0, c);
        c = mfma16(a1, b1, c);
        #pragma unroll
        for (int j = 0; j < 4; ++j) {
          const int rl = rt * 16 + l4 * 4 + j;
          const int r = I0 + rl;
          int dst, jp;
          if (jj >= 1023 - r) { dst = rl; jp = jj + r - 1023; }        // tail
          else               { dst = rl - 1; jp = jj + r + 1025; }     // wrap
          if (dst >= 0) sbd[swz(dst, jp)] = f2bf(c[j]);
        }
      }
    }
    if (I0 <= 990) {   // one extra BD row (I0+32) feeds last output row's wrap region
      const int arow = I0 + 32 + l15;
      bf16x8 a0 = *(const bf16x8*)(qvb + (size_t)arow * DKH + l4 * 8);
      bf16x8 a1 = *(const bf16x8*)(qvb + (size_t)arow * DKH + 32 + l4 * 8);
      #pragma unroll 4
      for (int nj = 0; nj < 16; ++nj) {
        const int jj = w * 256 + nj * 16 + l15;
        bf16x8 b0 = *(const bf16x8*)(pbh + (size_t)jj * DKH + l4 * 8);
        bf16x8 b1 = *(const bf16x8*)(pbh + (size_t)jj * DKH + 32 + l4 * 8);
        f32x4 c = {0.f, 0.f, 0.f, 0.f};
        c = mfma16(a0, b0, c);
        c = mfma16(a1, b1, c);
        if (l4 == 0 && jj <= 990 - I0)
          sbd[swz(31, jj + I0 + 1057)] = f2bf(c[0]);
      }
    }
    if (tid < 32) {    // the zero column injected by the pad/reshape trick
      const int jp = I0 + tid + 1025;
      if (jp < 2048) sbd[swz(tid, jp)] = 0;
    }
  }
  __syncthreads();

  // ---- P2: AC via MFMA, combine with shifted BD + additive mask ----
  f32x4 e[32];
  {
    const unsigned short* qub = qu + (size_t)bh * QL * DKH;
    const unsigned short* kbh = kb + (size_t)bh * TTOT * DKH;
    const unsigned short* mptr = mkb + ((size_t)b * QL + I0) * TTOT;
    const int arow = I0 + rt * 16 + l15;
    bf16x8 a0 = *(const bf16x8*)(qub + (size_t)arow * DKH + l4 * 8);
    bf16x8 a1 = *(const bf16x8*)(qub + (size_t)arow * DKH + 32 + l4 * 8);
    #pragma unroll
    for (int nj = 0; nj < 32; ++nj) {
      const int jp = cc * 512 + nj * 16 + l15;
      bf16x8 b0 = *(const bf16x8*)(kbh + (size_t)jp * DKH + l4 * 8);
      bf16x8 b1 = *(const bf16x8*)(kbh + (size_t)jp * DKH + 32 + l4 * 8);
      f32x4 c = {0.f, 0.f, 0.f, 0.f};
      c = mfma16(a0, b0, c);
      c = mfma16(a1, b1, c);
      #pragma unroll
      for (int j = 0; j < 4; ++j) {
        const int rl = rt * 16 + l4 * 4 + j;
        const float bd = bf2f(sbd[swz(rl, jp)]);
        const float mv = bf2f(mptr[(size_t)rl * TTOT + jp]);
        c[j] = (c[j] + bd) * 0.125f + mv;
      }
      e[nj] = c;
    }
  }

  // ---- P3: row max / sum (16-lane shuffle + cross-wave via LDS) ----
  float minv[4];
  {
    float mx[4] = {-3.0e38f, -3.0e38f, -3.0e38f, -3.0e38f};
    #pragma unroll
    for (int nj = 0; nj < 32; ++nj)
      #pragma unroll
      for (int j = 0; j < 4; ++j) mx[j] = fmaxf(mx[j], e[nj][j]);
    #pragma unroll
    for (int j = 0; j < 4; ++j) {
      mx[j] = fmaxf(mx[j], __shfl_xor(mx[j], 1, 64));
      mx[j] = fmaxf(mx[j], __shfl_xor(mx[j], 2, 64));
      mx[j] = fmaxf(mx[j], __shfl_xor(mx[j], 4, 64));
      mx[j] = fmaxf(mx[j], __shfl_xor(mx[j], 8, 64));
    }
    if (l15 == 0) {
      #pragma unroll
      for (int j = 0; j < 4; ++j) sred[0][cc][rt * 16 + l4 * 4 + j] = mx[j];
    }
  }
  __syncthreads();
  {
    float mr[4];
    #pragma unroll
    for (int j = 0; j < 4; ++j) {
      const int rl = rt * 16 + l4 * 4 + j;
      mr[j] = fmaxf(fmaxf(sred[0][0][rl], sred[0][1][rl]),
                    fmaxf(sred[0][2][rl], sred[0][3][rl]));
    }
    float sm[4] = {0.f, 0.f, 0.f, 0.f};
    #pragma unroll
    for (int nj = 0; nj < 32; ++nj)
      #pragma unroll
      for (int j = 0; j < 4; ++j) {
        const float p = __expf(e[nj][j] - mr[j]);
        e[nj][j] = p;
        sm[j] += p;
      }
    #pragma unroll
    for (int j = 0; j < 4; ++j) {
      sm[j] += __shfl_xor(sm[j], 1, 64);
      sm[j] += __shfl_xor(sm[j], 2, 64);
      sm[j] += __shfl_xor(sm[j], 4, 64);
      sm[j] += __shfl_xor(sm[j], 8, 64);
    }
    if (l15 == 0) {
      #pragma unroll
      for (int j = 0; j < 4; ++j) sred[1][cc][rt * 16 + l4 * 4 + j] = sm[j];
    }
  }
  __syncthreads();
  #pragma unroll
  for (int j = 0; j < 4; ++j) {
    const int rl = rt * 16 + l4 * 4 + j;
    const float s = sred[1][0][rl] + sred[1][1][rl] + sred[1][2][rl] + sred[1][3][rl];
    minv[j] = 1.0f / s;
  }

  // ---- P4: write aw (fp32 output) + bf16 aw back into LDS for PV ----
  {
    float* awb = awout + ((size_t)bh * QL + I0) * TTOT;
    #pragma unroll
    for (int nj = 0; nj < 32; ++nj) {
      const int jp = cc * 512 + nj * 16 + l15;
      #pragma unroll
      for (int j = 0; j < 4; ++j) {
        const int rl = rt * 16 + l4 * 4 + j;
        const float a = e[nj][j] * minv[j];
        awb[(size_t)rl * TTOT + jp] = a;
        sbd[swz(rl, jp)] = f2bf(a);
      }
    }
  }
  __syncthreads();

  // ---- P5: PV: each wave = (16 q-rows) x (16 dk cols), K = 2048 ----
  {
    const int ih = w >> 2, dc = w & 3;
    const unsigned short* vrow = vt + ((size_t)bh * DKH + dc * 16 + l15) * TTOT;
    const int row = ih * 16 + l15;
    const int rowbyte = row * 4096;
    const int sws = (row & 7) << 4;
    f32x4 pv = {0.f, 0.f, 0.f, 0.f};
    #pragma unroll 8
    for (int ks = 0; ks < 64; ++ks) {
      bf16x8 a = *(const bf16x8*)((const char*)sbd +
                  (rowbyte + (((ks * 64 + l4 * 16)) ^ sws)));
      bf16x8 vvf = *(const bf16x8*)(vrow + ks * 32 + l4 * 8);
      pv = mfma16(a, vvf, pv);
    }
    const int orow = I0 + ih * 16 + l4 * 4;
    const size_t obase = ((size_t)b * QL + orow) * 1024 + h * 64 + dc * 16 + l15;
    #pragma unroll
    for (int j = 0; j < 4; ++j) cvb[obase + (size_t)j * 1024] = f2bf(pv[j]);
  }
}

extern "C" void kernel_launch(void* const* d_in, const int* in_sizes, int n_in,
                              void* d_out, int out_size, void* d_ws, size_t ws_size,
                              hipStream_t stream) {
  (void)in_sizes; (void)n_in; (void)out_size; (void)ws_size;
  const float* key    = (const float*)d_in[0];
  const float* query  = (const float*)d_in[1];
  const float* memory = (const float*)d_in[2];
  const float* pos    = (const float*)d_in[3];
  const int*   mask   = (const int*)d_in[4];
  const float* u      = (const float*)d_in[5];
  const float* v      = (const float*)d_in[6];
  const float* Wk     = (const float*)d_in[7];
  const float* bk     = (const float*)d_in[8];
  const float* Wv     = (const float*)d_in[9];
  const float* bv     = (const float*)d_in[10];
  const float* Wq     = (const float*)d_in[11];
  const float* bq     = (const float*)d_in[12];
  const float* Wp     = (const float*)d_in[13];
  const float* bp     = (const float*)d_in[14];
  const float* Wo     = (const float*)d_in[15];
  const float* bo     = (const float*)d_in[16];

  float* outCV = (float*)d_out;
  float* outAW = outCV + 2097152;

  char* ws = (char*)d_ws;
  const size_t MB = (size_t)1 << 20;
  unsigned short* kbf  = (unsigned short*)(ws + 0);        // [bh][t][dk]   8MB
  unsigned short* vbf  = (unsigned short*)(ws + 8 * MB);   // [bh][t][dk]   8MB
  unsigned short* vtb  = (unsigned short*)(ws + 16 * MB);  // [bh][dk][t]   8MB
  unsigned short* qub  = (unsigned short*)(ws + 24 * MB);  // q+u           4MB
  unsigned short* qvb  = (unsigned short*)(ws + 28 * MB);  // q+v           4MB
  unsigned short* pbf  = (unsigned short*)(ws + 32 * MB);  // [h][t][dk]    4MB
  unsigned short* cvb  = (unsigned short*)(ws + 36 * MB);  // [b*Q][1024]   4MB
  unsigned short* kcat = (unsigned short*)(ws + 40 * MB);  // [b][t][1024]  8MB
  unsigned short* qry  = (unsigned short*)(ws + 48 * MB);  // 4MB
  unsigned short* posb = (unsigned short*)(ws + 52 * MB);  // 4MB
  unsigned short* wkb  = (unsigned short*)(ws + 56 * MB);
  unsigned short* wvb  = (unsigned short*)(ws + 58 * MB);
  unsigned short* wqb  = (unsigned short*)(ws + 60 * MB);
  unsigned short* wpb  = (unsigned short*)(ws + 62 * MB);
  unsigned short* wob  = (unsigned short*)(ws + 64 * MB);
  unsigned short* mkb  = (unsigned short*)(ws + 66 * MB);  // 8MB

  convert_all<<<2048, 256, 0, stream>>>(key, query, memory, pos, mask,
      Wk, Wv, Wq, Wp, Wo, kcat, qry, posb, wkb, wvb, wqb, wpb, wob, mkb);

  gemm_bt<0><<<dim3(8, 32), 256, 0, stream>>>(kcat, wkb, bk, nullptr, nullptr,
      kbf, nullptr, nullptr, 4096, 11);
  gemm_bt<0><<<dim3(8, 32), 256, 0, stream>>>(kcat, wvb, bv, nullptr, nullptr,
      vbf, nullptr, nullptr, 4096, 11);
  gemm_bt<1><<<dim3(8, 16), 256, 0, stream>>>(qry, wqb, bq, u, v,
      qub, qvb, nullptr, 2048, 10);
  gemm_bt<0><<<dim3(8, 16), 256, 0, stream>>>(posb, wpb, bp, nullptr, nullptr,
      pbf, nullptr, nullptr, 2048, 11);

  transpose_v<<<dim3(8, 32), 256, 0, stream>>>(vbf, vtb);

  attn_fused<<<dim3(32, 32), 512, 0, stream>>>(qub, qvb, kbf, pbf, vtb, mkb,
      outAW, cvb);

  gemm_bt<2><<<dim3(8, 16), 256, 0, stream>>>(cvb, wob, bo, nullptr, nullptr,
      nullptr, nullptr, outCV, 2048, 0);
}